// Round 1
// baseline (118.715 us; speedup 1.0000x reference)
//
#include <hip/hip_runtime.h>
#include <hip/hip_cooperative_groups.h>

namespace cg = cooperative_groups;

// ws layout: float wmse_part[256] | float mn_part[256] | float mx_part[256] | int cnt_part[256]

__global__ __launch_bounds__(256) void SPL_fused(const float* __restrict__ pred,
                                                 const float* __restrict__ tgt,
                                                 float* __restrict__ part,
                                                 float* __restrict__ out) {
    __shared__ float sP[1280], sT[1280];   // 10 rows x 128 cols, zero-padded
    __shared__ float vsP[256], vsT[256];   // vertical 9-sums
    __shared__ float red[12];
    __shared__ int   redi[4];
    __shared__ float bcast[2];

    cg::grid_group grid = cg::this_grid();

    int b = blockIdx.x;
    int t = threadIdx.x;
    int m  = b >> 6;              // image 0..3
    int r2 = (b & 63) << 1;       // first of the 2 output rows
    const float* p = pred + (m << 14);
    const float* q = tgt  + (m << 14);

    // ---- phase 1: box-mean distortion + wmse/min/max partials (identical math to kA) ----
#pragma unroll
    for (int s = 0; s < 5; ++s) {
        int k   = t + s * 256;    // 0..1279
        int rr  = k >> 7;
        int cc  = k & 127;
        int grw = r2 - 4 + rr;
        bool ok = (unsigned)grw < 128u;
        sP[k] = ok ? p[(grw << 7) + cc] : 0.f;
        sT[k] = ok ? q[(grw << 7) + cc] : 0.f;
    }
    __syncthreads();

    int orow = t >> 7;            // 0/1
    int col  = t & 127;
    int row  = r2 + orow;

    float vp = 0.f, vt = 0.f;
    int vb = orow * 128 + col;
#pragma unroll
    for (int di = 0; di < 9; ++di) {
        vp += sP[vb + di * 128];
        vt += sT[vb + di * 128];
    }
    vsP[t] = vp; vsT[t] = vt;
    __syncthreads();

    float sp = 0.f, st = 0.f;
    int rbase = t & ~127;
#pragma unroll
    for (int dj = -4; dj <= 4; ++dj) {
        int jj = col + dj;
        if ((unsigned)jj < 128u) { sp += vsP[rbase + jj]; st += vsT[rbase + jj]; }
    }

    int   rc  = min(row, 4) + min(127 - row, 4) + 1;
    int   cn  = min(col, 4) + min(127 - col, 4) + 1;
    float den = (float)(rc * cn);
    float pv  = sP[(orow + 4) * 128 + col];
    float tv  = sT[(orow + 4) * 128 + col];
    float pd  = pv - sp / den;     // kept in registers across grid.sync
    float td  = tv - st / den;

    // threshold-weighted MSE term
    float w = 1.f;
    if (tv >= 0.5f) w = 2.f;
    if (tv >= 2.f)  w = 5.f;
    if (tv >= 5.f)  w = 10.f;
    if (tv >= 10.f) w = 30.f;
    float d  = pv - tv;
    float s  = w * d * d;
    float mn = fminf(pd, td);
    float mx = fmaxf(pd, td);

    for (int o = 32; o > 0; o >>= 1) {
        s  += __shfl_down(s, o, 64);
        mn  = fminf(mn, __shfl_down(mn, o, 64));
        mx  = fmaxf(mx, __shfl_down(mx, o, 64));
    }
    int lane = t & 63, wid = t >> 6;
    if (lane == 0) { red[wid] = s; red[4 + wid] = mn; red[8 + wid] = mx; }
    __syncthreads();
    if (t == 0) {
        part[b]       = red[0] + red[1] + red[2] + red[3];
        part[256 + b] = fminf(fminf(red[4], red[5]), fminf(red[6], red[7]));
        part[512 + b] = fmaxf(fmaxf(red[8], red[9]), fmaxf(red[10], red[11]));
    }

    grid.sync();

    // ---- phase 2: every block redundantly reduces lo/hi (2 KB, L2-hit), then counts ----
    float mn2 = part[256 + t];
    float mx2 = part[512 + t];
    for (int o = 32; o > 0; o >>= 1) {
        mn2 = fminf(mn2, __shfl_down(mn2, o, 64));
        mx2 = fmaxf(mx2, __shfl_down(mx2, o, 64));
    }
    if (lane == 0) { red[4 + wid] = mn2; red[8 + wid] = mx2; }
    __syncthreads();
    if (t == 0) {
        bcast[0] = fminf(fminf(red[4], red[5]), fminf(red[6], red[7]));
        bcast[1] = fmaxf(fmaxf(red[8], red[9]), fmaxf(red[10], red[11]));
    }
    __syncthreads();
    float lo = bcast[0], hi = bcast[1];
    float dx = (hi - lo) / 999.0f;
    float inv_dx = 1.0f / dx;

    // per-pixel count of grid points x_k = lo + k*dx, k in [0,1000), inside [min,max)
    float a0 = fminf(pd, td);
    float b0 = fmaxf(pd, td);
    int ka = (int)ceilf((a0 - lo) * inv_dx);
    int kb = (int)ceilf((b0 - lo) * inv_dx);
    ka = max(ka, 0); kb = min(kb, 1000);
    int cnt = max(kb - ka, 0);

    for (int o = 32; o > 0; o >>= 1) cnt += __shfl_down(cnt, o, 64);
    if (lane == 0) redi[wid] = cnt;
    __syncthreads();
    if (t == 0) {
        ((int*)part)[768 + b] = redi[0] + redi[1] + redi[2] + redi[3];
    }

    grid.sync();

    // ---- phase 3: block 0 folds 256 count + wmse partials, writes the loss ----
    if (b == 0) {
        int   c  = ((const int*)part)[768 + t];
        float ss = part[t];
        for (int o = 32; o > 0; o >>= 1) {
            c  += __shfl_down(c, o, 64);
            ss += __shfl_down(ss, o, 64);
        }
        if (lane == 0) { redi[wid] = c; red[wid] = ss; }
        __syncthreads();
        if (t == 0) {
            long long tot = (long long)redi[0] + redi[1] + redi[2] + redi[3];
            float  wmse = (red[0] + red[1] + red[2] + red[3]) * (1.0f / 65536.0f);
            double crps = (double)tot * (double)dx / 65536.0;
            out[0] = 1e-4f * wmse + (float)crps;
        }
    }
}

extern "C" void kernel_launch(void* const* d_in, const int* in_sizes, int n_in,
                              void* d_out, int out_size, void* d_ws, size_t ws_size,
                              hipStream_t stream) {
    const float* pred = (const float*)d_in[0];
    const float* tgt  = (const float*)d_in[1];
    float* part = (float*)d_ws;    // 256 f32 wmse | 256 f32 min | 256 f32 max | 256 i32 cnt
    float* out  = (float*)d_out;

    void* args[] = { (void*)&pred, (void*)&tgt, (void*)&part, (void*)&out };
    hipLaunchCooperativeKernel((void*)SPL_fused, dim3(256), dim3(256), args, 0, stream);
}

// Round 2
// 65.470 us; speedup vs baseline: 1.8133x; 1.8133x over previous
//
#include <hip/hip_runtime.h>

// ws layout: float wmse_part[256] | float mn_part[256] | float mx_part[256]
//            | int cnt_accum, ticket (at part+768) | pad | float2 dist[65536] (at part+1024)

__global__ __launch_bounds__(256) void SPL_kA(const float* __restrict__ pred,
                                              const float* __restrict__ tgt,
                                              float* __restrict__ part,
                                              float2* __restrict__ dist) {
    __shared__ float sP[1280], sT[1280];   // 10 rows x 128 cols, zero-padded
    __shared__ float vsP[256], vsT[256];   // vertical 9-sums
    __shared__ float red[12];

    int b = blockIdx.x;
    int t = threadIdx.x;
    int m  = b >> 6;              // image 0..3
    int r2 = (b & 63) << 1;       // first of the 2 output rows
    const float* p = pred + (m << 14);
    const float* q = tgt  + (m << 14);

    // zero the kB accumulator/ticket (visible to kB via kernel boundary)
    if (b == 0 && t < 2) ((int*)(part + 768))[t] = 0;

    // stage rows r2-4 .. r2+5 (zero-pad out-of-image)
#pragma unroll
    for (int s = 0; s < 5; ++s) {
        int k   = t + s * 256;    // 0..1279
        int rr  = k >> 7;
        int cc  = k & 127;
        int grw = r2 - 4 + rr;
        bool ok = (unsigned)grw < 128u;
        sP[k] = ok ? p[(grw << 7) + cc] : 0.f;
        sT[k] = ok ? q[(grw << 7) + cc] : 0.f;
    }
    __syncthreads();

    int orow = t >> 7;            // 0/1
    int col  = t & 127;
    int row  = r2 + orow;

    // vertical 9-sum
    float vp = 0.f, vt = 0.f;
    int vb = orow * 128 + col;
#pragma unroll
    for (int di = 0; di < 9; ++di) {
        vp += sP[vb + di * 128];
        vt += sT[vb + di * 128];
    }
    vsP[t] = vp; vsT[t] = vt;
    __syncthreads();

    // horizontal 9-sum with column bounds
    float sp = 0.f, st = 0.f;
    int rbase = t & ~127;
#pragma unroll
    for (int dj = -4; dj <= 4; ++dj) {
        int jj = col + dj;
        if ((unsigned)jj < 128u) { sp += vsP[rbase + jj]; st += vsT[rbase + jj]; }
    }

    int   rc  = min(row, 4) + min(127 - row, 4) + 1;
    int   cn  = min(col, 4) + min(127 - col, 4) + 1;
    float den = (float)(rc * cn);
    float pv  = sP[(orow + 4) * 128 + col];
    float tv  = sT[(orow + 4) * 128 + col];
    float pd  = pv - sp / den;
    float td  = tv - st / den;

    dist[(b << 8) + t] = make_float2(pd, td);

    // threshold-weighted MSE term
    float w = 1.f;
    if (tv >= 0.5f) w = 2.f;
    if (tv >= 2.f)  w = 5.f;
    if (tv >= 5.f)  w = 10.f;
    if (tv >= 10.f) w = 30.f;
    float d  = pv - tv;
    float s  = w * d * d;
    float mn = fminf(pd, td);
    float mx = fmaxf(pd, td);

    for (int o = 32; o > 0; o >>= 1) {
        s  += __shfl_down(s, o, 64);
        mn  = fminf(mn, __shfl_down(mn, o, 64));
        mx  = fmaxf(mx, __shfl_down(mx, o, 64));
    }
    int lane = t & 63, wid = t >> 6;
    if (lane == 0) { red[wid] = s; red[4 + wid] = mn; red[8 + wid] = mx; }
    __syncthreads();
    if (t == 0) {
        part[b]       = red[0] + red[1] + red[2] + red[3];
        part[256 + b] = fminf(fminf(red[4], red[5]), fminf(red[6], red[7]));
        part[512 + b] = fmaxf(fmaxf(red[8], red[9]), fmaxf(red[10], red[11]));
    }
}

// 256 blocks x 256 threads: parallel CRPS count + atomic ticket finish
__global__ __launch_bounds__(256) void SPL_kB2(const float* __restrict__ part,
                                               const float2* __restrict__ dist,
                                               int* __restrict__ ctrs,
                                               float* __restrict__ out) {
    __shared__ float red[12];
    __shared__ int   redi[4];
    __shared__ int   sh_last;

    int b = blockIdx.x, t = threadIdx.x;
    int lane = t & 63, wid = t >> 6;

    // redundant per-block global lo/hi reduction over kA partials (3 KB, L2-hit)
    float mn = part[256 + t];
    float mx = part[512 + t];
    for (int o = 32; o > 0; o >>= 1) {
        mn = fminf(mn, __shfl_down(mn, o, 64));
        mx = fmaxf(mx, __shfl_down(mx, o, 64));
    }
    if (lane == 0) { red[4 + wid] = mn; red[8 + wid] = mx; }
    __syncthreads();
    float lo = fminf(fminf(red[4], red[5]), fminf(red[6], red[7]));
    float hi = fmaxf(fmaxf(red[8], red[9]), fmaxf(red[10], red[11]));
    float dx = (hi - lo) / 999.0f;
    float inv_dx = 1.0f / dx;

    // count grid points x_k = lo + k*dx, k in [0,1000), inside [min,max) per pixel
    float2 dpx = dist[(b << 8) + t];
    float a0 = fminf(dpx.x, dpx.y);
    float b0 = fmaxf(dpx.x, dpx.y);
    int ka = (int)ceilf((a0 - lo) * inv_dx);
    int kb = (int)ceilf((b0 - lo) * inv_dx);
    ka = max(ka, 0); kb = min(kb, 1000);
    int cnt = max(kb - ka, 0);

    for (int o = 32; o > 0; o >>= 1) cnt += __shfl_down(cnt, o, 64);
    if (lane == 0) redi[wid] = cnt;
    __syncthreads();

    if (t == 0) {
        int bc = redi[0] + redi[1] + redi[2] + redi[3];
        atomicAdd(&ctrs[0], bc);          // device-scope, coherent
        __threadfence();                  // order cnt-add before ticket-add
        int my = atomicAdd(&ctrs[1], 1);
        sh_last = (my == 255) ? 1 : 0;
    }
    __syncthreads();

    if (sh_last) {
        // last block folds the wmse partials and writes the loss
        float s = part[t];
        for (int o = 32; o > 0; o >>= 1) s += __shfl_down(s, o, 64);
        if (lane == 0) red[wid] = s;
        __syncthreads();
        if (t == 0) {
            int tot = atomicAdd(&ctrs[0], 0);   // coherent read of final total
            float  wmse = (red[0] + red[1] + red[2] + red[3]) * (1.0f / 65536.0f);
            double crps = (double)tot * (double)dx / 65536.0;
            out[0] = 1e-4f * wmse + (float)crps;
        }
    }
}

extern "C" void kernel_launch(void* const* d_in, const int* in_sizes, int n_in,
                              void* d_out, int out_size, void* d_ws, size_t ws_size,
                              hipStream_t stream) {
    const float* pred = (const float*)d_in[0];
    const float* tgt  = (const float*)d_in[1];
    float*  part = (float*)d_ws;                 // 768 floats + 2 ints
    float2* dist = (float2*)(part + 1024);       // 65536 float2 = 512 KB
    int*    ctrs = (int*)(part + 768);
    float*  out  = (float*)d_out;

    SPL_kA<<<256, 256, 0, stream>>>(pred, tgt, part, dist);
    SPL_kB2<<<256, 256, 0, stream>>>(part, dist, ctrs, out);
}